// Round 2
// baseline (971.642 us; speedup 1.0000x reference)
//
#include <hip/hip_runtime.h>

#define FIN 512
#define FMID 16
#define FOUT 64

// ---------- degree / CSR build ----------

__global__ void k_zero_i(int* __restrict__ p, int n) {
  int i = blockIdx.x * blockDim.x + threadIdx.x;
  if (i < n) p[i] = 0;
}

__global__ void k_hist(const int* __restrict__ dst, int* __restrict__ counts, int E) {
  int e = blockIdx.x * blockDim.x + threadIdx.x;
  if (e < E) atomicAdd(&counts[dst[e]], 1);
}

__global__ void k_dis(const int* __restrict__ counts, float* __restrict__ dis, int n) {
  int i = blockIdx.x * blockDim.x + threadIdx.x;
  if (i < n) dis[i] = rsqrtf(1.0f + (float)counts[i]);  // +1 = self-loop
}

// exclusive scan of counts[n] -> pre[n], 1024 elems/block (256 thr x 4)
__global__ __launch_bounds__(256) void k_scan1(const int* __restrict__ counts,
                                               int* __restrict__ pre,
                                               int* __restrict__ bsum, int n) {
  __shared__ int lds[256];
  const int t = threadIdx.x;
  const int base = blockIdx.x * 1024 + t * 4;
  int c[4], s = 0;
#pragma unroll
  for (int u = 0; u < 4; ++u) {
    int idx = base + u;
    c[u] = (idx < n) ? counts[idx] : 0;
    s += c[u];
  }
  lds[t] = s;
  __syncthreads();
  for (int off = 1; off < 256; off <<= 1) {
    int v = (t >= off) ? lds[t - off] : 0;
    __syncthreads();
    lds[t] += v;
    __syncthreads();
  }
  int run = lds[t] - s;  // exclusive prefix of this thread within block
  if (t == 255) bsum[blockIdx.x] = lds[255];
#pragma unroll
  for (int u = 0; u < 4; ++u) {
    int idx = base + u;
    if (idx < n) pre[idx] = run;
    run += c[u];
  }
}

// exclusive scan of bsum[nb] in place; nb <= 256
__global__ __launch_bounds__(256) void k_scan2(int* __restrict__ bsum, int nb) {
  __shared__ int lds[256];
  const int t = threadIdx.x;
  int v = (t < nb) ? bsum[t] : 0;
  lds[t] = v;
  __syncthreads();
  for (int off = 1; off < 256; off <<= 1) {
    int u = (t >= off) ? lds[t - off] : 0;
    __syncthreads();
    lds[t] += u;
    __syncthreads();
  }
  if (t < nb) bsum[t] = lds[t] - v;
}

// row_start[i] = pre[i] + bsum[i/1024] (in place on pre); row_cur[i] = row_start[i]
__global__ void k_scan3(int* __restrict__ row_start, const int* __restrict__ bsum,
                        int* __restrict__ row_cur, int n) {
  int i = blockIdx.x * blockDim.x + threadIdx.x;
  if (i < n) {
    int v = row_start[i] + bsum[i >> 10];
    row_start[i] = v;
    row_cur[i] = v;
  }
}

// scatter edges into dst-sorted slots; after this row_cur[i] == row_start[i+1]
__global__ void k_scatter(const int* __restrict__ src, const int* __restrict__ dst,
                          int* __restrict__ row_cur, int* __restrict__ srcn, int E) {
  int e = blockIdx.x * blockDim.x + threadIdx.x;
  if (e < E) {
    int pos = atomicAdd(&row_cur[dst[e]], 1);
    srcn[pos] = src[e];
  }
}

// ---------- h = x @ W1 : one thread per node, W1 via wave-uniform scalar loads ----------

__global__ __launch_bounds__(256) void k_gemm1(const float* __restrict__ x,
                                               const float* __restrict__ W1,
                                               float* __restrict__ h, int n) {
  int node = blockIdx.x * 256 + threadIdx.x;
  if (node >= n) return;
  const float4* xr = (const float4*)(x + (size_t)node * FIN);
  float acc[FMID];
#pragma unroll
  for (int j = 0; j < FMID; ++j) acc[j] = 0.f;
  for (int k4 = 0; k4 < FIN / 4; ++k4) {
    float4 xv = xr[k4];
    const float* wr = W1 + k4 * 4 * FMID;  // uniform across lanes -> s_load
#pragma unroll
    for (int j = 0; j < FMID; ++j) acc[j] += xv.x * wr[j];
#pragma unroll
    for (int j = 0; j < FMID; ++j) acc[j] += xv.y * wr[FMID + j];
#pragma unroll
    for (int j = 0; j < FMID; ++j) acc[j] += xv.z * wr[2 * FMID + j];
#pragma unroll
    for (int j = 0; j < FMID; ++j) acc[j] += xv.w * wr[3 * FMID + j];
  }
  float4* hr = (float4*)(h + (size_t)node * FMID);
#pragma unroll
  for (int j4 = 0; j4 < FMID / 4; ++j4)
    hr[j4] = make_float4(acc[4 * j4], acc[4 * j4 + 1], acc[4 * j4 + 2], acc[4 * j4 + 3]);
}

// ---------- CSR gather propagation: one wave per node, fused self-loop/bias/relu ----------

__global__ __launch_bounds__(256) void k_gather(const float* __restrict__ hin,
                                                const int* __restrict__ srcn,
                                                const int* __restrict__ row_start,
                                                const int* __restrict__ row_end,
                                                const float* __restrict__ dis,
                                                const float* __restrict__ bias,
                                                float* __restrict__ out, int n, int relu) {
  const int lane = threadIdx.x & 63;
  const int g = lane >> 4, j = lane & 15;
  const int node = blockIdx.x * 4 + (threadIdx.x >> 6);
  if (node >= n) return;
  const float disd = dis[node];
  const int beg = row_start[node], end = row_end[node];
  float acc = 0.f;
  for (int e = beg + g; e < end; e += 4) {
    int s = srcn[e];
    float w = dis[s] * disd;
    acc += hin[(size_t)s * FMID + j] * w;
  }
  acc += __shfl_xor(acc, 16);
  acc += __shfl_xor(acc, 32);
  if (g == 0) {
    float v = acc + hin[(size_t)node * FMID + j] * disd * disd;
    if (bias) v += bias[j];
    if (relu) v = fmaxf(v, 0.f);
    out[(size_t)node * FMID + j] = v;
  }
}

// ---------- out = log_softmax(a2 @ W2 + b2) : one wave per node ----------

__global__ __launch_bounds__(256) void k_out(const float* __restrict__ a2,
                                             const float* __restrict__ W2,
                                             const float* __restrict__ b2,
                                             float* __restrict__ out, int n) {
  __shared__ float w[FMID * FOUT];  // 4 KB; lane reads 64 consecutive -> 2-way (free)
  for (int idx = threadIdx.x; idx < FMID * FOUT; idx += 256) w[idx] = W2[idx];
  __syncthreads();
  const int lane = threadIdx.x & 63;
  const int node = blockIdx.x * 4 + (threadIdx.x >> 6);
  if (node >= n) return;
  const float* ar = a2 + (size_t)node * FMID;  // wave-uniform row -> s_load
  float o = b2[lane];
#pragma unroll
  for (int k = 0; k < FMID; ++k) o += ar[k] * w[k * FOUT + lane];
  float m = o;
#pragma unroll
  for (int off = 32; off >= 1; off >>= 1) m = fmaxf(m, __shfl_xor(m, off));
  float e = __expf(o - m);
  float s = e;
#pragma unroll
  for (int off = 32; off >= 1; off >>= 1) s += __shfl_xor(s, off);
  out[(size_t)node * FOUT + lane] = o - m - __logf(s);
}

// ---------- launch ----------

extern "C" void kernel_launch(void* const* d_in, const int* in_sizes, int n_in,
                              void* d_out, int out_size, void* d_ws, size_t ws_size,
                              hipStream_t stream) {
  const float* x  = (const float*)d_in[0];
  const int* edge = (const int*)d_in[1];
  const float* W1 = (const float*)d_in[2];
  const float* b1 = (const float*)d_in[3];
  const float* W2 = (const float*)d_in[4];
  const float* b2 = (const float*)d_in[5];
  float* out = (float*)d_out;

  const int N = in_sizes[0] / FIN;  // 100000
  const int E = in_sizes[1] / 2;    // 3200000
  const int* src = edge;
  const int* dst = edge + E;

  const int NA = (N + 15) & ~15;
  // ws layout (4-byte words):
  // counts[NA] | row_start[NA] | row_cur[NA] | dis[NA] | h[16NA] (reused as a2)
  // | a1[16NA] | srcn[E] | bsum[256]
  int*   counts    = (int*)d_ws;
  int*   row_start = counts + NA;
  int*   row_cur   = row_start + NA;
  float* dis       = (float*)(row_cur + NA);
  float* h         = dis + NA;
  float* a1        = h + (size_t)16 * NA;
  int*   srcn      = (int*)(a1 + (size_t)16 * NA);
  int*   bsum      = srcn + E;

  const int T = 256;
  const int nbN = (N + T - 1) / T;
  const int nbE = (E + T - 1) / T;
  const int nScan = (N + 1023) / 1024;

  // degree + dis
  k_zero_i<<<nbN, T, 0, stream>>>(counts, N);
  k_hist  <<<nbE, T, 0, stream>>>(dst, counts, E);
  k_dis   <<<nbN, T, 0, stream>>>(counts, dis, N);

  // CSR build (dst-sorted src list)
  k_scan1  <<<nScan, T, 0, stream>>>(counts, row_start, bsum, N);
  k_scan2  <<<1, T, 0, stream>>>(bsum, nScan);
  k_scan3  <<<nbN, T, 0, stream>>>(row_start, bsum, row_cur, N);
  k_scatter<<<nbE, T, 0, stream>>>(src, dst, row_cur, srcn, E);

  // layer 1: transform then propagate (16-dim), bias+relu fused
  k_gemm1 <<<(N + T - 1) / T, T, 0, stream>>>(x, W1, h, N);
  k_gather<<<(N + 3) / 4, T, 0, stream>>>(h, srcn, row_start, row_cur, dis, b1, a1, N, 1);

  // layer 2: propagate first at 16-dim (P(h1 W2) == (P h1) W2); a2 overlays h
  k_gather<<<(N + 3) / 4, T, 0, stream>>>(a1, srcn, row_start, row_cur, dis, nullptr, h, N, 0);

  // transform + log_softmax
  k_out<<<(N + 3) / 4, T, 0, stream>>>(h, W2, b2, out, N);
}